// Round 1
// baseline (85.976 us; speedup 1.0000x reference)
//
#include <hip/hip_runtime.h>
#include <math.h>

// Problem constants: bs=32, en=256, dx=512, dz=256, heads=8, dh=32, L=1280.
//
// Key insight: the additive mask is block-diagonal eyes, so
//   q <  256: atten row = one-hot at l=q  (softmax of a single element)
//   q = 256+j: atten has exactly 4 nonzeros at l in {q, 512+j, 768+j, 1024+j}
// and those 4 keys are column 256+j of centered state and column j of each
// centered obs. We fold Wk into the query side:
//   score[b,j,h,m] = ( sum_e kb_m[e] * (wu[j,h,e]+wv[b,h,e]) + ubk+vbk ) / sqrt(32)
// with kb_m = raw_m - mean_m + pe, handled via raw/pe/ones dot rows.
//
// ws layout (floats):
//   pe   [32][256]             @ 0
//   u    [256][256]            @ 8192      (Q[256:]@Wq)
//   v    [32][256]             @ 73728     (pe@Wq + bq)
//   wu2  [8][256e][256j]       @ 81920
//   wv   [32][8][256e]         @ 606208
//   ubk  [256][8]              @ 671744
//   vbk  [32][8]               @ 673792
//   a    [32][256][4]          @ 674048    (head-averaged softmax weights)
// total 706816 floats = 2.83 MB

// ---------------------------------------------------------------- k_uv
// blocks 0..255  : j-block -> u[j][f], ubk[j][h]
// blocks 256..287: b-block -> pe[b][:], v[b][f], vbk[b][h]
__global__ void k_uv(const float* __restrict__ Q, const float* __restrict__ Wq,
                     const float* __restrict__ bq, const float* __restrict__ bk,
                     float* __restrict__ pe, float* __restrict__ u,
                     float* __restrict__ v, float* __restrict__ ubk,
                     float* __restrict__ vbk) {
  __shared__ float row[256];
  const int f = threadIdx.x;
  const int blk = blockIdx.x;
  float rv;
  if (blk < 256) {
    rv = Q[(256 + blk) * 256 + f];
  } else {
    const int b = blk - 256;
    // sinusoidal PE over the BATCH axis (faithful quirk): pos=b, d_model=256
    const float dv = expf(-9.210340371976184f * (float)((f >> 1) << 1) * (1.0f / 256.0f));
    const float ang = (float)b * dv;
    rv = (f & 1) ? cosf(ang) : sinf(ang);
    pe[b * 256 + f] = rv;
  }
  row[f] = rv;
  __syncthreads();
  float acc = (blk < 256) ? 0.0f : bq[f];
  for (int e = 0; e < 256; ++e) acc += row[e] * Wq[e * 256 + f];
  if (blk < 256) u[blk * 256 + f] = acc;
  else           v[(blk - 256) * 256 + f] = acc;
  // qh . bk contribution, reduced per 32-lane head group
  float val = acc * bk[f];
  val += __shfl_xor(val, 1);  val += __shfl_xor(val, 2);
  val += __shfl_xor(val, 4);  val += __shfl_xor(val, 8);
  val += __shfl_xor(val, 16);
  if ((f & 31) == 0) {
    const int h = f >> 5;
    if (blk < 256) ubk[blk * 8 + h] = val;
    else           vbk[(blk - 256) * 8 + h] = val;
  }
}

// ---------------------------------------------------------------- k_w
// y=0: block e, thread j: wu2[h][e][j] = sum_d u[j][h*32+d]*Wk[e][h*32+d]
// y=1: block e, thread b<32: wv[b][h][e] = sum_d v[b][h*32+d]*Wk[e][h*32+d]
__global__ void k_w(const float* __restrict__ Wk, const float* __restrict__ u,
                    const float* __restrict__ v, float* __restrict__ wu2,
                    float* __restrict__ wv) {
  __shared__ float wrow[256];
  const int e = blockIdx.x;
  const int t = threadIdx.x;
  wrow[t] = Wk[e * 256 + t];
  __syncthreads();
  if (blockIdx.y == 0) {
    const float* ur = u + t * 256;
#pragma unroll
    for (int h = 0; h < 8; ++h) {
      float acc = 0.0f;
#pragma unroll
      for (int d = 0; d < 32; ++d) acc += ur[h * 32 + d] * wrow[h * 32 + d];
      wu2[(h * 256 + e) * 256 + t] = acc;
    }
  } else if (t < 32) {
    const float* vr = v + t * 256;
#pragma unroll
    for (int h = 0; h < 8; ++h) {
      float acc = 0.0f;
#pragma unroll
      for (int d = 0; d < 32; ++d) acc += vr[h * 32 + d] * wrow[h * 32 + d];
      wv[(t * 8 + h) * 256 + e] = acc;
    }
  }
}

// ---------------------------------------------------------------- k_score
// block (jt, b), 64 lanes: lane = jl(0..15) + 16*eg(0..3). Each lane owns
// j = jt*16+jl, accumulates over its e-quarter, then 2-stage shfl reduce.
__global__ void k_score(const float* __restrict__ state, const float* __restrict__ o0,
                        const float* __restrict__ o1, const float* __restrict__ o2,
                        const float* __restrict__ pe, const float* __restrict__ wu2,
                        const float* __restrict__ wv, const float* __restrict__ ubk,
                        const float* __restrict__ vbk, float* __restrict__ a) {
  const int lane = threadIdx.x;
  const int jl = lane & 15;
  const int eg = lane >> 4;
  const int j = blockIdx.x * 16 + jl;
  const int b = blockIdx.y;

  float dR0[8], dR1[8], dR2[8], dR3[8], dP[8], dO[8];
#pragma unroll
  for (int h = 0; h < 8; ++h) { dR0[h]=0.f; dR1[h]=0.f; dR2[h]=0.f; dR3[h]=0.f; dP[h]=0.f; dO[h]=0.f; }
  float sm0 = 0.f, sm1 = 0.f, sm2 = 0.f, sm3 = 0.f;

  const float* ps = state + (size_t)b * 256 * 512 + 256 + j;
  const float* p0 = o0 + (size_t)b * 256 * 256 + j;
  const float* p1 = o1 + (size_t)b * 256 * 256 + j;
  const float* p2 = o2 + (size_t)b * 256 * 256 + j;
  const float* pp = pe + b * 256;
  const float* pwu = wu2 + j;            // + (h*256+e)*256
  const float* pwv = wv + b * 8 * 256;   // + h*256+e

  for (int it = 0; it < 64; ++it) {
    const int e = eg * 64 + it;
    const float s  = ps[(size_t)e * 512];
    const float x0 = p0[(size_t)e * 256];
    const float x1 = p1[(size_t)e * 256];
    const float x2 = p2[(size_t)e * 256];
    const float pv = pp[e];
    sm0 += s; sm1 += x0; sm2 += x1; sm3 += x2;
#pragma unroll
    for (int h = 0; h < 8; ++h) {
      const float w = pwu[(size_t)(h * 256 + e) * 256] + pwv[h * 256 + e];
      dR0[h] += s * w;  dR1[h] += x0 * w;
      dR2[h] += x1 * w; dR3[h] += x2 * w;
      dP[h]  += pv * w; dO[h]  += w;
    }
  }
  // reduce across the 4 e-groups (lane bits 4 and 5)
#pragma unroll
  for (int h = 0; h < 8; ++h) {
    dR0[h] += __shfl_xor(dR0[h], 16); dR0[h] += __shfl_xor(dR0[h], 32);
    dR1[h] += __shfl_xor(dR1[h], 16); dR1[h] += __shfl_xor(dR1[h], 32);
    dR2[h] += __shfl_xor(dR2[h], 16); dR2[h] += __shfl_xor(dR2[h], 32);
    dR3[h] += __shfl_xor(dR3[h], 16); dR3[h] += __shfl_xor(dR3[h], 32);
    dP[h]  += __shfl_xor(dP[h], 16);  dP[h]  += __shfl_xor(dP[h], 32);
    dO[h]  += __shfl_xor(dO[h], 16);  dO[h]  += __shfl_xor(dO[h], 32);
  }
  sm0 += __shfl_xor(sm0, 16); sm0 += __shfl_xor(sm0, 32);
  sm1 += __shfl_xor(sm1, 16); sm1 += __shfl_xor(sm1, 32);
  sm2 += __shfl_xor(sm2, 16); sm2 += __shfl_xor(sm2, 32);
  sm3 += __shfl_xor(sm3, 16); sm3 += __shfl_xor(sm3, 32);

  if (eg != 0) return;

  const float m0 = sm0 * (1.f / 256.f), m1 = sm1 * (1.f / 256.f);
  const float m2 = sm2 * (1.f / 256.f), m3 = sm3 * (1.f / 256.f);
  const float inv = 0.17677669529663687f;  // 1/sqrt(32)
  float am0 = 0.f, am1 = 0.f, am2 = 0.f, am3 = 0.f;
#pragma unroll
  for (int h = 0; h < 8; ++h) {
    const float qb = ubk[j * 8 + h] + vbk[b * 8 + h];
    const float c = dP[h] + qb;
    const float s0 = (dR0[h] - m0 * dO[h] + c) * inv;
    const float s1 = (dR1[h] - m1 * dO[h] + c) * inv;
    const float s2 = (dR2[h] - m2 * dO[h] + c) * inv;
    const float s3 = (dR3[h] - m3 * dO[h] + c) * inv;
    const float mx = fmaxf(fmaxf(s0, s1), fmaxf(s2, s3));
    const float e0 = expf(s0 - mx), e1 = expf(s1 - mx);
    const float e2 = expf(s2 - mx), e3 = expf(s3 - mx);
    const float r = 1.f / (e0 + e1 + e2 + e3);
    am0 += e0 * r; am1 += e1 * r; am2 += e2 * r; am3 += e3 * r;
  }
  float4 o = make_float4(am0 * 0.125f, am1 * 0.125f, am2 * 0.125f, am3 * 0.125f);
  *(float4*)(a + ((size_t)(b * 256 + j) << 2)) = o;
}

// ---------------------------------------------------------------- k_ns
// new_state[b,e,q]: q<256 -> state[b,e,q]; q=256+j -> 4-term weighted sum.
__global__ void k_ns(const float* __restrict__ state, const float* __restrict__ o0,
                     const float* __restrict__ o1, const float* __restrict__ o2,
                     const float* __restrict__ a, float* __restrict__ out0) {
  const int t = threadIdx.x;   // 128
  const int e = blockIdx.x;    // 256
  const int b = blockIdx.y;    // 32
  const size_t rowS = ((size_t)b * 256 + e) * 512;
  const size_t rowO = ((size_t)b * 256 + e) * 256;
  if (t < 64) {
    const float4 vv = *(const float4*)(state + rowS + t * 4);
    *(float4*)(out0 + rowS + t * 4) = vv;
  } else {
    const int q0 = t * 4;
    const int j0 = q0 - 256;
    const float4 s  = *(const float4*)(state + rowS + q0);
    const float4 x0 = *(const float4*)(o0 + rowO + j0);
    const float4 x1 = *(const float4*)(o1 + rowO + j0);
    const float4 x2 = *(const float4*)(o2 + rowO + j0);
    const float rs[4] = {s.x, s.y, s.z, s.w};
    const float r0[4] = {x0.x, x0.y, x0.z, x0.w};
    const float r1[4] = {x1.x, x1.y, x1.z, x1.w};
    const float r2[4] = {x2.x, x2.y, x2.z, x2.w};
    float ro[4];
#pragma unroll
    for (int k = 0; k < 4; ++k) {
      const float4 aa = *(const float4*)(a + (((size_t)b * 256) + (j0 + k)) * 4);
      ro[k] = aa.x * rs[k] + aa.y * r0[k] + aa.z * r1[k] + aa.w * r2[k];
    }
    const float4 o = make_float4(ro[0], ro[1], ro[2], ro[3]);
    *(float4*)(out0 + rowS + q0) = o;
  }
}

// ---------------------------------------------------------------- k_at
// atten[b,q,:]: zeros except one-hot (q<256) or 4 sparse weights (q>=256).
__global__ void k_at(const float* __restrict__ a, float* __restrict__ out1) {
  const int t = threadIdx.x;   // 320 (1280/4)
  const int q = blockIdx.x;    // 512
  const int b = blockIdx.y;    // 32
  const int l0 = t * 4;
  float v0 = 0.f, v1 = 0.f, v2 = 0.f, v3 = 0.f;
  if (q < 256) {
    if (q == l0) v0 = 1.f; else if (q == l0 + 1) v1 = 1.f;
    else if (q == l0 + 2) v2 = 1.f; else if (q == l0 + 3) v3 = 1.f;
  } else {
    const int j = q - 256;
    const int s = j & 3;                       // all 4 cols share q mod 4
    const float* ap = a + (((size_t)b * 256) + j) * 4;
    float av = 0.f; bool hit = false;
    if (l0 == (q & ~3))              { av = ap[0]; hit = true; }
    else if (l0 == ((512 + j) & ~3)) { av = ap[1]; hit = true; }
    else if (l0 == ((768 + j) & ~3)) { av = ap[2]; hit = true; }
    else if (l0 == ((1024 + j) & ~3)){ av = ap[3]; hit = true; }
    if (hit) { if (s == 0) v0 = av; else if (s == 1) v1 = av; else if (s == 2) v2 = av; else v3 = av; }
  }
  const float4 o = make_float4(v0, v1, v2, v3);
  *(float4*)(out1 + ((size_t)b * 512 + q) * 1280 + l0) = o;
}

extern "C" void kernel_launch(void* const* d_in, const int* in_sizes, int n_in,
                              void* d_out, int out_size, void* d_ws, size_t ws_size,
                              hipStream_t stream) {
  const float* state = (const float*)d_in[0];
  const float* obs0  = (const float*)d_in[1];
  const float* obs1  = (const float*)d_in[2];
  const float* obs2  = (const float*)d_in[3];
  const float* Q     = (const float*)d_in[4];
  const float* Wq    = (const float*)d_in[5];
  const float* bq    = (const float*)d_in[6];
  const float* Wk    = (const float*)d_in[7];
  const float* bk    = (const float*)d_in[8];

  float* out0 = (float*)d_out;                       // new_state [32,256,512]
  float* out1 = out0 + (size_t)32 * 256 * 512;       // atten [32,512,1280]

  float* ws  = (float*)d_ws;
  float* pe  = ws;              // 8192
  float* u   = pe + 8192;       // 65536
  float* v   = u + 65536;       // 8192
  float* wu2 = v + 8192;        // 524288
  float* wv  = wu2 + 524288;    // 65536
  float* ubk = wv + 65536;      // 2048
  float* vbk = ubk + 2048;      // 256
  float* a   = vbk + 256;       // 32768

  k_uv<<<288, 256, 0, stream>>>(Q, Wq, bq, bk, pe, u, v, ubk, vbk);
  k_w<<<dim3(256, 2), 256, 0, stream>>>(Wk, u, v, wu2, wv);
  k_score<<<dim3(16, 32), 64, 0, stream>>>(state, obs0, obs1, obs2, pe, wu2, wv, ubk, vbk, a);
  k_ns<<<dim3(256, 32), 128, 0, stream>>>(state, obs0, obs1, obs2, a, out0);
  k_at<<<dim3(512, 32), 320, 0, stream>>>(a, out1);
}

// Round 2
// 80.853 us; speedup vs baseline: 1.0634x; 1.0634x over previous
//
#include <hip/hip_runtime.h>
#include <math.h>

// Problem constants: bs=32, en=256, dx=512, dz=256, heads=8, dh=32, L=1280.
//
// Mask is block-diagonal eyes: q<256 -> one-hot row; q=256+j -> exactly 4
// nonzeros {q, 512+j, 768+j, 1024+j} = col 256+j of centered state and col j
// of each centered obs. Wk is folded into the query side:
//   score[b,j,h,m] = ( sum_e kb_m[e]*(wu[j,h,e]+wv[b,h,e]) + ubk+vbk ) / sqrt(32)
// with kb_m = raw_m - mean_m + pe, via raw/pe/ones dot rows.
//
// ws layout (floats):
//   pe   [32][256]             @ 0
//   u    [256][256]            @ 8192      (Q[256:]@Wq)
//   v    [32][256]             @ 73728     (pe@Wq + bq)
//   wu2  [8][256e][256j]       @ 81920
//   wv   [32][8][256e]         @ 606208
//   ubk  [256][8]              @ 671744
//   vbk  [32][8]               @ 673792
//   a    [32][256][4]          @ 674048    (head-averaged softmax weights)

// ---------------------------------------------------------------- k_uv
__global__ void k_uv(const float* __restrict__ Q, const float* __restrict__ Wq,
                     const float* __restrict__ bq, const float* __restrict__ bk,
                     float* __restrict__ pe, float* __restrict__ u,
                     float* __restrict__ v, float* __restrict__ ubk,
                     float* __restrict__ vbk) {
  __shared__ float row[256];
  const int f = threadIdx.x;
  const int blk = blockIdx.x;
  float rv;
  if (blk < 256) {
    rv = Q[(256 + blk) * 256 + f];
  } else {
    const int b = blk - 256;
    // sinusoidal PE over the BATCH axis (faithful quirk): pos=b, d_model=256
    const float dv = expf(-9.210340371976184f * (float)((f >> 1) << 1) * (1.0f / 256.0f));
    const float ang = (float)b * dv;
    rv = (f & 1) ? cosf(ang) : sinf(ang);
    pe[b * 256 + f] = rv;
  }
  row[f] = rv;
  __syncthreads();
  float acc = (blk < 256) ? 0.0f : bq[f];
  for (int e = 0; e < 256; ++e) acc += row[e] * Wq[e * 256 + f];
  if (blk < 256) u[blk * 256 + f] = acc;
  else           v[(blk - 256) * 256 + f] = acc;
  float val = acc * bk[f];
  val += __shfl_xor(val, 1);  val += __shfl_xor(val, 2);
  val += __shfl_xor(val, 4);  val += __shfl_xor(val, 8);
  val += __shfl_xor(val, 16);
  if ((f & 31) == 0) {
    const int h = f >> 5;
    if (blk < 256) ubk[blk * 8 + h] = val;
    else           vbk[(blk - 256) * 8 + h] = val;
  }
}

// ---------------------------------------------------------------- k_w
__global__ void k_w(const float* __restrict__ Wk, const float* __restrict__ u,
                    const float* __restrict__ v, float* __restrict__ wu2,
                    float* __restrict__ wv) {
  __shared__ float wrow[256];
  const int e = blockIdx.x;
  const int t = threadIdx.x;
  wrow[t] = Wk[e * 256 + t];
  __syncthreads();
  if (blockIdx.y == 0) {
    const float* ur = u + t * 256;
#pragma unroll
    for (int h = 0; h < 8; ++h) {
      float acc = 0.0f;
#pragma unroll
      for (int d = 0; d < 32; ++d) acc += ur[h * 32 + d] * wrow[h * 32 + d];
      wu2[(h * 256 + e) * 256 + t] = acc;
    }
  } else if (t < 32) {
    const float* vr = v + t * 256;
#pragma unroll
    for (int h = 0; h < 8; ++h) {
      float acc = 0.0f;
#pragma unroll
      for (int d = 0; d < 32; ++d) acc += vr[h * 32 + d] * wrow[h * 32 + d];
      wv[(t * 8 + h) * 256 + e] = acc;
    }
  }
}

// ---------------------------------------------------------------- k_score
// block (jt, b), 512 threads = 8 waves. t = jl(0..15) + 16*eg(0..31).
// Lane owns j = jt*16+jl, e in [eg*8, eg*8+8). Reduce: shfl over lane bits
// 4,5 (eg low bits) then LDS across the 8 waves. wv[b], pe[b] staged in LDS.
__global__ __launch_bounds__(512)
void k_score(const float* __restrict__ state, const float* __restrict__ o0,
             const float* __restrict__ o1, const float* __restrict__ o2,
             const float* __restrict__ pe, const float* __restrict__ wu2,
             const float* __restrict__ wv, const float* __restrict__ ubk,
             const float* __restrict__ vbk, float* __restrict__ a) {
  const int t = threadIdx.x;
  const int jl = t & 15;
  const int eg = t >> 4;           // 0..31
  const int j = blockIdx.x * 16 + jl;
  const int b = blockIdx.y;

  __shared__ float s_wv[2048];     // wv[b][h][e]
  __shared__ float s_pe[256];      // pe[b][e]
  __shared__ float s_part[8][16][52];

  for (int i = t; i < 2048; i += 512) s_wv[i] = wv[b * 2048 + i];
  if (t < 256) s_pe[t] = pe[b * 256 + t];
  __syncthreads();

  // acc[h*6+c]: c=0..3 -> dR(state,o0,o1,o2), c=4 -> dP(pe), c=5 -> dO(ones)
  float acc[48];
#pragma unroll
  for (int k = 0; k < 48; ++k) acc[k] = 0.f;
  float sm0 = 0.f, sm1 = 0.f, sm2 = 0.f, sm3 = 0.f;

  const float* ps = state + (size_t)b * 256 * 512 + 256 + j;
  const float* p0 = o0 + (size_t)b * 256 * 256 + j;
  const float* p1 = o1 + (size_t)b * 256 * 256 + j;
  const float* p2 = o2 + (size_t)b * 256 * 256 + j;
  const float* pwu = wu2 + j;      // + (h*256+e)*256

  const int e0 = eg * 8;
#pragma unroll
  for (int it = 0; it < 8; ++it) {
    const int e = e0 + it;
    const float s  = ps[(size_t)e * 512];
    const float x0 = p0[(size_t)e * 256];
    const float x1 = p1[(size_t)e * 256];
    const float x2 = p2[(size_t)e * 256];
    const float pv = s_pe[e];
    sm0 += s; sm1 += x0; sm2 += x1; sm3 += x2;
#pragma unroll
    for (int h = 0; h < 8; ++h) {
      const float w = pwu[(size_t)(h * 256 + e) * 256] + s_wv[h * 256 + e];
      acc[h * 6 + 0] += s * w;  acc[h * 6 + 1] += x0 * w;
      acc[h * 6 + 2] += x1 * w; acc[h * 6 + 3] += x2 * w;
      acc[h * 6 + 4] += pv * w; acc[h * 6 + 5] += w;
    }
  }

  // reduce across lane bits 4,5 (4 eg values within the wave)
#pragma unroll
  for (int k = 0; k < 48; ++k) {
    acc[k] += __shfl_xor(acc[k], 16);
    acc[k] += __shfl_xor(acc[k], 32);
  }
  sm0 += __shfl_xor(sm0, 16); sm0 += __shfl_xor(sm0, 32);
  sm1 += __shfl_xor(sm1, 16); sm1 += __shfl_xor(sm1, 32);
  sm2 += __shfl_xor(sm2, 16); sm2 += __shfl_xor(sm2, 32);
  sm3 += __shfl_xor(sm3, 16); sm3 += __shfl_xor(sm3, 32);

  if ((t & 48) == 0) {
    const int w = t >> 6;
    float* p = &s_part[w][jl][0];
#pragma unroll
    for (int k = 0; k < 48; ++k) p[k] = acc[k];
    p[48] = sm0; p[49] = sm1; p[50] = sm2; p[51] = sm3;
  }
  __syncthreads();

  if (t < 16) {
    float tot[52];
#pragma unroll
    for (int k = 0; k < 52; ++k) {
      float s = 0.f;
#pragma unroll
      for (int w = 0; w < 8; ++w) s += s_part[w][t][k];
      tot[k] = s;
    }
    const int jj = blockIdx.x * 16 + t;
    const float m0 = tot[48] * (1.f / 256.f), m1 = tot[49] * (1.f / 256.f);
    const float m2 = tot[50] * (1.f / 256.f), m3 = tot[51] * (1.f / 256.f);
    const float inv = 0.17677669529663687f;  // 1/sqrt(32)
    float am0 = 0.f, am1 = 0.f, am2 = 0.f, am3 = 0.f;
#pragma unroll
    for (int h = 0; h < 8; ++h) {
      const float qb = ubk[jj * 8 + h] + vbk[b * 8 + h];
      const float c = tot[h * 6 + 4] + qb;
      const float s0 = (tot[h * 6 + 0] - m0 * tot[h * 6 + 5] + c) * inv;
      const float s1 = (tot[h * 6 + 1] - m1 * tot[h * 6 + 5] + c) * inv;
      const float s2 = (tot[h * 6 + 2] - m2 * tot[h * 6 + 5] + c) * inv;
      const float s3 = (tot[h * 6 + 3] - m3 * tot[h * 6 + 5] + c) * inv;
      const float mx = fmaxf(fmaxf(s0, s1), fmaxf(s2, s3));
      const float e0 = expf(s0 - mx), e1 = expf(s1 - mx);
      const float e2 = expf(s2 - mx), e3 = expf(s3 - mx);
      const float r = 1.f / (e0 + e1 + e2 + e3);
      am0 += e0 * r; am1 += e1 * r; am2 += e2 * r; am3 += e3 * r;
    }
    float4 o = make_float4(am0 * 0.125f, am1 * 0.125f, am2 * 0.125f, am3 * 0.125f);
    *(float4*)(a + ((size_t)(b * 256 + jj) << 2)) = o;
  }
}

// ---------------------------------------------------------------- k_ns
__global__ void k_ns(const float* __restrict__ state, const float* __restrict__ o0,
                     const float* __restrict__ o1, const float* __restrict__ o2,
                     const float* __restrict__ a, float* __restrict__ out0) {
  const int t = threadIdx.x;   // 128
  const int e = blockIdx.x;    // 256
  const int b = blockIdx.y;    // 32
  const size_t rowS = ((size_t)b * 256 + e) * 512;
  const size_t rowO = ((size_t)b * 256 + e) * 256;
  if (t < 64) {
    const float4 vv = *(const float4*)(state + rowS + t * 4);
    *(float4*)(out0 + rowS + t * 4) = vv;
  } else {
    const int q0 = t * 4;
    const int j0 = q0 - 256;
    const float4 s  = *(const float4*)(state + rowS + q0);
    const float4 x0 = *(const float4*)(o0 + rowO + j0);
    const float4 x1 = *(const float4*)(o1 + rowO + j0);
    const float4 x2 = *(const float4*)(o2 + rowO + j0);
    const float rs[4] = {s.x, s.y, s.z, s.w};
    const float r0[4] = {x0.x, x0.y, x0.z, x0.w};
    const float r1[4] = {x1.x, x1.y, x1.z, x1.w};
    const float r2[4] = {x2.x, x2.y, x2.z, x2.w};
    float ro[4];
#pragma unroll
    for (int k = 0; k < 4; ++k) {
      const float4 aa = *(const float4*)(a + (((size_t)b * 256) + (j0 + k)) * 4);
      ro[k] = aa.x * rs[k] + aa.y * r0[k] + aa.z * r1[k] + aa.w * r2[k];
    }
    const float4 o = make_float4(ro[0], ro[1], ro[2], ro[3]);
    *(float4*)(out0 + rowS + q0) = o;
  }
}

// ---------------------------------------------------------------- k_at
__global__ void k_at(const float* __restrict__ a, float* __restrict__ out1) {
  const int t = threadIdx.x;   // 320 (1280/4)
  const int q = blockIdx.x;    // 512
  const int b = blockIdx.y;    // 32
  const int l0 = t * 4;
  float v0 = 0.f, v1 = 0.f, v2 = 0.f, v3 = 0.f;
  if (q < 256) {
    if (q == l0) v0 = 1.f; else if (q == l0 + 1) v1 = 1.f;
    else if (q == l0 + 2) v2 = 1.f; else if (q == l0 + 3) v3 = 1.f;
  } else {
    const int j = q - 256;
    const int s = j & 3;
    const float* ap = a + (((size_t)b * 256) + j) * 4;
    float av = 0.f; bool hit = false;
    if (l0 == (q & ~3))              { av = ap[0]; hit = true; }
    else if (l0 == ((512 + j) & ~3)) { av = ap[1]; hit = true; }
    else if (l0 == ((768 + j) & ~3)) { av = ap[2]; hit = true; }
    else if (l0 == ((1024 + j) & ~3)){ av = ap[3]; hit = true; }
    if (hit) { if (s == 0) v0 = av; else if (s == 1) v1 = av; else if (s == 2) v2 = av; else v3 = av; }
  }
  const float4 o = make_float4(v0, v1, v2, v3);
  *(float4*)(out1 + ((size_t)b * 512 + q) * 1280 + l0) = o;
}

extern "C" void kernel_launch(void* const* d_in, const int* in_sizes, int n_in,
                              void* d_out, int out_size, void* d_ws, size_t ws_size,
                              hipStream_t stream) {
  const float* state = (const float*)d_in[0];
  const float* obs0  = (const float*)d_in[1];
  const float* obs1  = (const float*)d_in[2];
  const float* obs2  = (const float*)d_in[3];
  const float* Q     = (const float*)d_in[4];
  const float* Wq    = (const float*)d_in[5];
  const float* bq    = (const float*)d_in[6];
  const float* Wk    = (const float*)d_in[7];
  const float* bk    = (const float*)d_in[8];

  float* out0 = (float*)d_out;                       // new_state [32,256,512]
  float* out1 = out0 + (size_t)32 * 256 * 512;       // atten [32,512,1280]

  float* ws  = (float*)d_ws;
  float* pe  = ws;              // 8192
  float* u   = pe + 8192;       // 65536
  float* v   = u + 65536;       // 8192
  float* wu2 = v + 8192;        // 524288
  float* wv  = wu2 + 524288;    // 65536
  float* ubk = wv + 65536;      // 2048
  float* vbk = ubk + 2048;      // 256
  float* a   = vbk + 256;       // 32768

  k_uv<<<288, 256, 0, stream>>>(Q, Wq, bq, bk, pe, u, v, ubk, vbk);
  k_w<<<dim3(256, 2), 256, 0, stream>>>(Wk, u, v, wu2, wv);
  k_score<<<dim3(16, 32), 512, 0, stream>>>(state, obs0, obs1, obs2, pe, wu2, wv, ubk, vbk, a);
  k_ns<<<dim3(256, 32), 128, 0, stream>>>(state, obs0, obs1, obs2, a, out0);
  k_at<<<dim3(512, 32), 320, 0, stream>>>(a, out1);
}